// Round 1
// baseline (888.586 us; speedup 1.0000x reference)
//
#include <hip/hip_runtime.h>

#define DIV_UP(a,b) (((a)+(b)-1)/(b))

// ---------------- CSR build ----------------

__global__ void k_count(const int* __restrict__ dst, int* __restrict__ deg, int E) {
    int e = blockIdx.x * blockDim.x + threadIdx.x;
    if (e < E) atomicAdd(&deg[dst[e]], 1);
}

__global__ void k_blocksum(const int* __restrict__ deg, int* __restrict__ bsum, int N) {
    __shared__ int s[1024];
    int i = blockIdx.x * 1024 + threadIdx.x;
    s[threadIdx.x] = (i < N) ? deg[i] : 0;
    __syncthreads();
    for (int off = 512; off > 0; off >>= 1) {
        if (threadIdx.x < off) s[threadIdx.x] += s[threadIdx.x + off];
        __syncthreads();
    }
    if (threadIdx.x == 0) bsum[blockIdx.x] = s[0];
}

__global__ void k_scanbsum(const int* __restrict__ bsum, int* __restrict__ boff, int nb) {
    __shared__ int s[1024];
    int v = (threadIdx.x < nb) ? bsum[threadIdx.x] : 0;
    s[threadIdx.x] = v;
    __syncthreads();
    for (int off = 1; off < 1024; off <<= 1) {
        int t = (threadIdx.x >= off) ? s[threadIdx.x - off] : 0;
        __syncthreads();
        s[threadIdx.x] += t;
        __syncthreads();
    }
    if (threadIdx.x < nb) boff[threadIdx.x] = s[threadIdx.x] - v;
}

__global__ void k_scanfinal(const int* __restrict__ deg, const int* __restrict__ boff,
                            int* __restrict__ rowptr, int* __restrict__ cursor,
                            float* __restrict__ inv_sqrt, int N) {
    __shared__ int s[1024];
    int i = blockIdx.x * 1024 + threadIdx.x;
    int v = (i < N) ? deg[i] : 0;
    s[threadIdx.x] = v;
    __syncthreads();
    for (int off = 1; off < 1024; off <<= 1) {
        int t = (threadIdx.x >= off) ? s[threadIdx.x - off] : 0;
        __syncthreads();
        s[threadIdx.x] += t;
        __syncthreads();
    }
    if (i < N) {
        int excl = s[threadIdx.x] - v + boff[blockIdx.x];
        rowptr[i] = excl;
        cursor[i] = excl;
        inv_sqrt[i] = rsqrtf((float)(v + 1));   // +1: self-loop
        if (i == N - 1) rowptr[N] = excl + v;
    }
}

__global__ void k_fill(const int* __restrict__ src, const int* __restrict__ dst,
                       int* __restrict__ cursor, int* __restrict__ col, int E) {
    int e = blockIdx.x * blockDim.x + threadIdx.x;
    if (e < E) {
        int p = atomicAdd(&cursor[dst[e]], 1);
        col[p] = src[e];
    }
}

// ---------------- GEMM: out[n][c] = inv_sqrt[n] * sum_k in[n][k]*W[k][c] ----------------
// 128x128 W, 8 rows per block, thread = (row_local, 4-col group)

__global__ void k_gemm128(const float* __restrict__ in, const float* __restrict__ W,
                          const float* __restrict__ inv_sqrt, float* __restrict__ out, int N) {
    __shared__ float xs[8][128];
    int t  = threadIdx.x;
    int lr = t >> 5;       // 0..7
    int lc = t & 31;       // 0..31
    int row = blockIdx.x * 8 + lr;

    float4 xv = make_float4(0.f, 0.f, 0.f, 0.f);
    if (row < N) xv = *(const float4*)(in + (size_t)row * 128 + lc * 4);
    *(float4*)(&xs[lr][lc * 4]) = xv;
    __syncthreads();

    float4 acc = make_float4(0.f, 0.f, 0.f, 0.f);
    const float4* W4 = (const float4*)W;
    #pragma unroll 8
    for (int k = 0; k < 128; k++) {
        float xk = xs[lr][k];
        float4 w = W4[k * 32 + lc];
        acc.x += xk * w.x;
        acc.y += xk * w.y;
        acc.z += xk * w.z;
        acc.w += xk * w.w;
    }
    if (row < N) {
        float s = inv_sqrt[row];
        acc.x *= s; acc.y *= s; acc.z *= s; acc.w *= s;
        *(float4*)(out + (size_t)row * 128 + lc * 4) = acc;
    }
}

// ---------------- Aggregate: h[n] = relu(inv_sqrt[n]*(sum_{e in CSR[n]} g[col[e]] + g[n]) + b) ----------------
// one wave per node, float2 per lane

__global__ void k_aggregate(const float* __restrict__ g, const int* __restrict__ rowptr,
                            const int* __restrict__ col, const float* __restrict__ inv_sqrt,
                            const float* __restrict__ bias, float* __restrict__ out, int N) {
    int wid  = (blockIdx.x * blockDim.x + threadIdx.x) >> 6;   // node
    int lane = threadIdx.x & 63;
    if (wid >= N) return;

    int start = rowptr[wid];
    int end   = rowptr[wid + 1];

    float2 acc = make_float2(0.f, 0.f);
    for (int j0 = start; j0 < end; j0 += 64) {
        int rem = end - j0;
        int myc = (lane < rem) ? col[j0 + lane] : 0;
        int cnt = rem < 64 ? rem : 64;
        for (int tt = 0; tt < cnt; tt++) {
            int s = __shfl(myc, tt);
            float2 v = ((const float2*)(g + (size_t)s * 128))[lane];
            acc.x += v.x;
            acc.y += v.y;
        }
    }
    float2 sv = ((const float2*)(g + (size_t)wid * 128))[lane];
    acc.x += sv.x;
    acc.y += sv.y;

    float is = inv_sqrt[wid];
    float2 b = ((const float2*)bias)[lane];
    float ox = fmaxf(is * acc.x + b.x, 0.f);
    float oy = fmaxf(is * acc.y + b.y, 0.f);
    ((float2*)(out + (size_t)wid * 128))[lane] = make_float2(ox, oy);
}

// ---------------- Pool: per-graph sums + counts (batch is sorted) ----------------
// block = 128 threads (one per feature), handles 256 consecutive nodes

__global__ void k_pool(const float* __restrict__ h, const int* __restrict__ batch,
                       float* __restrict__ pooled, int* __restrict__ counts, int N) {
    int f = threadIdx.x;            // 0..127
    int start = blockIdx.x * 256;
    int end = start + 256; if (end > N) end = N;
    if (start >= N) return;

    int cur = batch[start];
    float acc = 0.f;
    int cnt = 0;
    for (int r = start; r < end; r++) {
        int gi = batch[r];
        if (gi != cur) {
            atomicAdd(&pooled[(size_t)cur * 128 + f], acc);
            if (f == 0) atomicAdd(&counts[cur], cnt);
            acc = 0.f; cnt = 0; cur = gi;
        }
        acc += h[(size_t)r * 128 + f];
        cnt++;
    }
    atomicAdd(&pooled[(size_t)cur * 128 + f], acc);
    if (f == 0) atomicAdd(&counts[cur], cnt);
}

// ---------------- MLP head: out = relu(mean @ Wc1 + bc1) @ Wc2 + bc2 ----------------
// one block per graph, 64 threads

__global__ void k_mlp(const float* __restrict__ pooled, const int* __restrict__ counts,
                      const float* __restrict__ Wc1, const float* __restrict__ bc1,
                      const float* __restrict__ Wc2, const float* __restrict__ bc2,
                      float* __restrict__ out, int G) {
    int g = blockIdx.x;
    int j = threadIdx.x;    // 0..63
    __shared__ float pm[128];
    __shared__ float z[64];

    float invc = 1.0f / fmaxf((float)counts[g], 1.0f);
    pm[j]      = pooled[(size_t)g * 128 + j] * invc;
    pm[j + 64] = pooled[(size_t)g * 128 + 64 + j] * invc;
    __syncthreads();

    float a = bc1[j];
    #pragma unroll 8
    for (int k = 0; k < 128; k++) a += pm[k] * Wc1[k * 64 + j];
    z[j] = fmaxf(a, 0.f);
    __syncthreads();

    if (j < 8) {
        float o = bc2[j];
        #pragma unroll 8
        for (int k = 0; k < 64; k++) o += z[k] * Wc2[k * 8 + j];
        out[(size_t)g * 8 + j] = o;
    }
}

// ---------------- launch ----------------

extern "C" void kernel_launch(void* const* d_in, const int* in_sizes, int n_in,
                              void* d_out, int out_size, void* d_ws, size_t ws_size,
                              hipStream_t stream) {
    const float* x    = (const float*)d_in[0];
    const int*   ei   = (const int*)d_in[1];
    const int*   batch= (const int*)d_in[2];
    const float* W1   = (const float*)d_in[4];
    const float* b1   = (const float*)d_in[5];
    const float* W2   = (const float*)d_in[6];
    const float* b2   = (const float*)d_in[7];
    const float* Wc1  = (const float*)d_in[8];
    const float* bc1  = (const float*)d_in[9];
    const float* Wc2  = (const float*)d_in[10];
    const float* bc2  = (const float*)d_in[11];
    float* out = (float*)d_out;

    const int N = in_sizes[0] / 128;
    const int E = in_sizes[1] / 2;
    const int G = out_size / 8;

    const int* src = ei;
    const int* dst = ei + E;

    // workspace carve-up
    char* p = (char*)d_ws;
    auto alloc = [&](size_t bytes) {
        char* q = p;
        p += (bytes + 255) & ~(size_t)255;
        return q;
    };
    float* bufA     = (float*)alloc((size_t)N * 128 * 4);
    float* bufB     = (float*)alloc((size_t)N * 128 * 4);
    int*   deg      = (int*)  alloc((size_t)N * 4);
    int*   rowptr   = (int*)  alloc(((size_t)N + 1) * 4);
    int*   cursor   = (int*)  alloc((size_t)N * 4);
    int*   colA     = (int*)  alloc((size_t)E * 4);
    float* inv_sqrt = (float*)alloc((size_t)N * 4);
    int*   bsum     = (int*)  alloc(1024 * 4);
    int*   boff     = (int*)  alloc(1024 * 4);
    float* pooled   = (float*)alloc((size_t)G * 128 * 4);
    int*   counts   = (int*)  alloc((size_t)G * 4);

    const int nb = DIV_UP(N, 1024);

    hipMemsetAsync(deg, 0, (size_t)N * 4, stream);
    hipMemsetAsync(pooled, 0, (size_t)G * 128 * 4, stream);
    hipMemsetAsync(counts, 0, (size_t)G * 4, stream);

    // CSR build
    k_count<<<DIV_UP(E, 256), 256, 0, stream>>>(dst, deg, E);
    k_blocksum<<<nb, 1024, 0, stream>>>(deg, bsum, N);
    k_scanbsum<<<1, 1024, 0, stream>>>(bsum, boff, nb);
    k_scanfinal<<<nb, 1024, 0, stream>>>(deg, boff, rowptr, cursor, inv_sqrt, N);
    k_fill<<<DIV_UP(E, 256), 256, 0, stream>>>(src, dst, cursor, colA, E);

    // layer 1
    k_gemm128<<<DIV_UP(N, 8), 256, 0, stream>>>(x, W1, inv_sqrt, bufA, N);
    k_aggregate<<<DIV_UP(N, 4), 256, 0, stream>>>(bufA, rowptr, colA, inv_sqrt, b1, bufB, N);

    // layer 2
    k_gemm128<<<DIV_UP(N, 8), 256, 0, stream>>>(bufB, W2, inv_sqrt, bufA, N);
    k_aggregate<<<DIV_UP(N, 4), 256, 0, stream>>>(bufA, rowptr, colA, inv_sqrt, b2, bufB, N);

    // pool + head
    k_pool<<<DIV_UP(N, 256), 128, 0, stream>>>(bufB, batch, pooled, counts, N);
    k_mlp<<<G, 64, 0, stream>>>(pooled, counts, Wc1, bc1, Wc2, bc2, out, G);
}

// Round 2
// 638.120 us; speedup vs baseline: 1.3925x; 1.3925x over previous
//
#include <hip/hip_runtime.h>

#define DIV_UP(a,b) (((a)+(b)-1)/(b))

// ---------------- CSR build ----------------

__global__ void k_count(const int* __restrict__ dst, int* __restrict__ deg, int E) {
    int e = blockIdx.x * blockDim.x + threadIdx.x;
    if (e < E) atomicAdd(&deg[dst[e]], 1);
}

__global__ void k_blocksum(const int* __restrict__ deg, int* __restrict__ bsum, int N) {
    __shared__ int s[1024];
    int i = blockIdx.x * 1024 + threadIdx.x;
    s[threadIdx.x] = (i < N) ? deg[i] : 0;
    __syncthreads();
    for (int off = 512; off > 0; off >>= 1) {
        if (threadIdx.x < off) s[threadIdx.x] += s[threadIdx.x + off];
        __syncthreads();
    }
    if (threadIdx.x == 0) bsum[blockIdx.x] = s[0];
}

__global__ void k_scanbsum(const int* __restrict__ bsum, int* __restrict__ boff, int nb) {
    __shared__ int s[1024];
    int v = (threadIdx.x < nb) ? bsum[threadIdx.x] : 0;
    s[threadIdx.x] = v;
    __syncthreads();
    for (int off = 1; off < 1024; off <<= 1) {
        int t = (threadIdx.x >= off) ? s[threadIdx.x - off] : 0;
        __syncthreads();
        s[threadIdx.x] += t;
        __syncthreads();
    }
    if (threadIdx.x < nb) boff[threadIdx.x] = s[threadIdx.x] - v;
}

__global__ void k_scanfinal(const int* __restrict__ deg, const int* __restrict__ boff,
                            int* __restrict__ rowptr, int* __restrict__ cursor,
                            float* __restrict__ inv_sqrt, int N) {
    __shared__ int s[1024];
    int i = blockIdx.x * 1024 + threadIdx.x;
    int v = (i < N) ? deg[i] : 0;
    s[threadIdx.x] = v;
    __syncthreads();
    for (int off = 1; off < 1024; off <<= 1) {
        int t = (threadIdx.x >= off) ? s[threadIdx.x - off] : 0;
        __syncthreads();
        s[threadIdx.x] += t;
        __syncthreads();
    }
    if (i < N) {
        int excl = s[threadIdx.x] - v + boff[blockIdx.x];
        rowptr[i] = excl;
        cursor[i] = excl;
        inv_sqrt[i] = rsqrtf((float)(v + 1));   // +1: self-loop
        if (i == N - 1) rowptr[N] = excl + v;
    }
}

__global__ void k_fill(const int* __restrict__ src, const int* __restrict__ dst,
                       int* __restrict__ cursor, int* __restrict__ col, int E) {
    int e = blockIdx.x * blockDim.x + threadIdx.x;
    if (e < E) {
        int p = atomicAdd(&cursor[dst[e]], 1);
        col[p] = src[e];
    }
}

// ---------------- Register-tiled GEMM ----------------
// out[n][c] = inv_sqrt[n] * sum_k in[n][k]*W[k][c]
// block = 256 threads, tile 128 rows x 128 cols, thread = 8x8 outputs, BK=32.
// xsT: x-tile transposed [k][row] (+4 pad); ws: W-tile row-major [k][col] (+4 pad).
// Wave lane layout: 8 row-groups x 8 col-groups -> all LDS b128 reads <=2-way (free).

__global__ __launch_bounds__(256, 3) void k_gemm_rt(const float* __restrict__ in,
                          const float* __restrict__ W,
                          const float* __restrict__ inv_sqrt,
                          float* __restrict__ out, int N) {
    __shared__ float xsT[32][132];
    __shared__ float ws[32][132];

    const int t = threadIdx.x;
    const int row0 = blockIdx.x * 128;
    const int lane = t & 63;
    const int wave = t >> 6;
    const int rg = ((wave >> 1) << 3) + (lane >> 3);  // 0..15 row group
    const int cg = ((wave & 1) << 3) + (lane & 7);    // 0..15 col group

    const float4* in4 = (const float4*)in;
    const float4* W4  = (const float4*)W;

    float4 acc[8][2];
    #pragma unroll
    for (int i = 0; i < 8; i++) {
        acc[i][0] = make_float4(0.f, 0.f, 0.f, 0.f);
        acc[i][1] = make_float4(0.f, 0.f, 0.f, 0.f);
    }

    const bool full = (row0 + 128 <= N);

    for (int kt = 0; kt < 4; kt++) {
        // stage x-tile (transposed into LDS)
        #pragma unroll
        for (int i = 0; i < 4; i++) {
            int idx = t + i * 256;
            int r  = idx >> 3;
            int c4 = idx & 7;
            int row = row0 + r;
            float4 v = make_float4(0.f, 0.f, 0.f, 0.f);
            if (full || row < N) v = in4[(size_t)row * 32 + kt * 8 + c4];
            xsT[c4 * 4 + 0][r] = v.x;
            xsT[c4 * 4 + 1][r] = v.y;
            xsT[c4 * 4 + 2][r] = v.z;
            xsT[c4 * 4 + 3][r] = v.w;
        }
        // stage W-tile
        #pragma unroll
        for (int i = 0; i < 4; i++) {
            int idx = t + i * 256;
            int kk = idx >> 5;
            int c4 = idx & 31;
            *(float4*)&ws[kk][c4 * 4] = W4[(size_t)(kt * 32 + kk) * 32 + c4];
        }
        __syncthreads();

        #pragma unroll 8
        for (int k = 0; k < 32; k++) {
            float4 a0 = *(const float4*)&xsT[k][rg * 8];
            float4 a1 = *(const float4*)&xsT[k][rg * 8 + 4];
            float4 b0 = *(const float4*)&ws[k][cg * 8];
            float4 b1 = *(const float4*)&ws[k][cg * 8 + 4];
            float av[8] = {a0.x, a0.y, a0.z, a0.w, a1.x, a1.y, a1.z, a1.w};
            #pragma unroll
            for (int i = 0; i < 8; i++) {
                acc[i][0].x += av[i] * b0.x;
                acc[i][0].y += av[i] * b0.y;
                acc[i][0].z += av[i] * b0.z;
                acc[i][0].w += av[i] * b0.w;
                acc[i][1].x += av[i] * b1.x;
                acc[i][1].y += av[i] * b1.y;
                acc[i][1].z += av[i] * b1.z;
                acc[i][1].w += av[i] * b1.w;
            }
        }
        __syncthreads();
    }

    // epilogue: scale by inv_sqrt[row], write float4 pairs
    #pragma unroll
    for (int i = 0; i < 8; i++) {
        int row = row0 + rg * 8 + i;
        if (full || row < N) {
            float s = inv_sqrt[row];
            float4 o0 = acc[i][0], o1 = acc[i][1];
            o0.x *= s; o0.y *= s; o0.z *= s; o0.w *= s;
            o1.x *= s; o1.y *= s; o1.z *= s; o1.w *= s;
            float4* o = (float4*)(out + (size_t)row * 128);
            o[cg * 2]     = o0;
            o[cg * 2 + 1] = o1;
        }
    }
}

// ---------------- Aggregate: h[n] = relu(inv_sqrt[n]*(sum_{e in CSR[n]} g[col[e]] + g[n]) + b) ----------------
// one wave per node, float2 per lane

__global__ void k_aggregate(const float* __restrict__ g, const int* __restrict__ rowptr,
                            const int* __restrict__ col, const float* __restrict__ inv_sqrt,
                            const float* __restrict__ bias, float* __restrict__ out, int N) {
    int wid  = (blockIdx.x * blockDim.x + threadIdx.x) >> 6;   // node
    int lane = threadIdx.x & 63;
    if (wid >= N) return;

    int start = rowptr[wid];
    int end   = rowptr[wid + 1];

    float2 acc = make_float2(0.f, 0.f);
    for (int j0 = start; j0 < end; j0 += 64) {
        int rem = end - j0;
        int myc = (lane < rem) ? col[j0 + lane] : 0;
        int cnt = rem < 64 ? rem : 64;
        for (int tt = 0; tt < cnt; tt++) {
            int s = __shfl(myc, tt);
            float2 v = ((const float2*)(g + (size_t)s * 128))[lane];
            acc.x += v.x;
            acc.y += v.y;
        }
    }
    float2 sv = ((const float2*)(g + (size_t)wid * 128))[lane];
    acc.x += sv.x;
    acc.y += sv.y;

    float is = inv_sqrt[wid];
    float2 b = ((const float2*)bias)[lane];
    float ox = fmaxf(is * acc.x + b.x, 0.f);
    float oy = fmaxf(is * acc.y + b.y, 0.f);
    ((float2*)(out + (size_t)wid * 128))[lane] = make_float2(ox, oy);
}

// ---------------- Pool: per-graph sums + counts (batch is sorted) ----------------

__global__ void k_pool(const float* __restrict__ h, const int* __restrict__ batch,
                       float* __restrict__ pooled, int* __restrict__ counts, int N) {
    int f = threadIdx.x;            // 0..127
    int start = blockIdx.x * 256;
    int end = start + 256; if (end > N) end = N;
    if (start >= N) return;

    int cur = batch[start];
    float acc = 0.f;
    int cnt = 0;
    for (int r = start; r < end; r++) {
        int gi = batch[r];
        if (gi != cur) {
            atomicAdd(&pooled[(size_t)cur * 128 + f], acc);
            if (f == 0) atomicAdd(&counts[cur], cnt);
            acc = 0.f; cnt = 0; cur = gi;
        }
        acc += h[(size_t)r * 128 + f];
        cnt++;
    }
    atomicAdd(&pooled[(size_t)cur * 128 + f], acc);
    if (f == 0) atomicAdd(&counts[cur], cnt);
}

// ---------------- MLP head ----------------

__global__ void k_mlp(const float* __restrict__ pooled, const int* __restrict__ counts,
                      const float* __restrict__ Wc1, const float* __restrict__ bc1,
                      const float* __restrict__ Wc2, const float* __restrict__ bc2,
                      float* __restrict__ out, int G) {
    int g = blockIdx.x;
    int j = threadIdx.x;    // 0..63
    __shared__ float pm[128];
    __shared__ float z[64];

    float invc = 1.0f / fmaxf((float)counts[g], 1.0f);
    pm[j]      = pooled[(size_t)g * 128 + j] * invc;
    pm[j + 64] = pooled[(size_t)g * 128 + 64 + j] * invc;
    __syncthreads();

    float a = bc1[j];
    #pragma unroll 8
    for (int k = 0; k < 128; k++) a += pm[k] * Wc1[k * 64 + j];
    z[j] = fmaxf(a, 0.f);
    __syncthreads();

    if (j < 8) {
        float o = bc2[j];
        #pragma unroll 8
        for (int k = 0; k < 64; k++) o += z[k] * Wc2[k * 8 + j];
        out[(size_t)g * 8 + j] = o;
    }
}

// ---------------- launch ----------------

extern "C" void kernel_launch(void* const* d_in, const int* in_sizes, int n_in,
                              void* d_out, int out_size, void* d_ws, size_t ws_size,
                              hipStream_t stream) {
    const float* x    = (const float*)d_in[0];
    const int*   ei   = (const int*)d_in[1];
    const int*   batch= (const int*)d_in[2];
    const float* W1   = (const float*)d_in[4];
    const float* b1   = (const float*)d_in[5];
    const float* W2   = (const float*)d_in[6];
    const float* b2   = (const float*)d_in[7];
    const float* Wc1  = (const float*)d_in[8];
    const float* bc1  = (const float*)d_in[9];
    const float* Wc2  = (const float*)d_in[10];
    const float* bc2  = (const float*)d_in[11];
    float* out = (float*)d_out;

    const int N = in_sizes[0] / 128;
    const int E = in_sizes[1] / 2;
    const int G = out_size / 8;

    const int* src = ei;
    const int* dst = ei + E;

    // workspace carve-up
    char* p = (char*)d_ws;
    auto alloc = [&](size_t bytes) {
        char* q = p;
        p += (bytes + 255) & ~(size_t)255;
        return q;
    };
    float* bufA     = (float*)alloc((size_t)N * 128 * 4);
    float* bufB     = (float*)alloc((size_t)N * 128 * 4);
    int*   deg      = (int*)  alloc((size_t)N * 4);
    int*   rowptr   = (int*)  alloc(((size_t)N + 1) * 4);
    int*   cursor   = (int*)  alloc((size_t)N * 4);
    int*   colA     = (int*)  alloc((size_t)E * 4);
    float* inv_sqrt = (float*)alloc((size_t)N * 4);
    int*   bsum     = (int*)  alloc(1024 * 4);
    int*   boff     = (int*)  alloc(1024 * 4);
    float* pooled   = (float*)alloc((size_t)G * 128 * 4);
    int*   counts   = (int*)  alloc((size_t)G * 4);

    const int nb = DIV_UP(N, 1024);

    hipMemsetAsync(deg, 0, (size_t)N * 4, stream);
    hipMemsetAsync(pooled, 0, (size_t)G * 128 * 4, stream);
    hipMemsetAsync(counts, 0, (size_t)G * 4, stream);

    // CSR build
    k_count<<<DIV_UP(E, 256), 256, 0, stream>>>(dst, deg, E);
    k_blocksum<<<nb, 1024, 0, stream>>>(deg, bsum, N);
    k_scanbsum<<<1, 1024, 0, stream>>>(bsum, boff, nb);
    k_scanfinal<<<nb, 1024, 0, stream>>>(deg, boff, rowptr, cursor, inv_sqrt, N);
    k_fill<<<DIV_UP(E, 256), 256, 0, stream>>>(src, dst, cursor, colA, E);

    // layer 1
    k_gemm_rt<<<DIV_UP(N, 128), 256, 0, stream>>>(x, W1, inv_sqrt, bufA, N);
    k_aggregate<<<DIV_UP(N, 4), 256, 0, stream>>>(bufA, rowptr, colA, inv_sqrt, b1, bufB, N);

    // layer 2
    k_gemm_rt<<<DIV_UP(N, 128), 256, 0, stream>>>(bufB, W2, inv_sqrt, bufA, N);
    k_aggregate<<<DIV_UP(N, 4), 256, 0, stream>>>(bufA, rowptr, colA, inv_sqrt, b2, bufB, N);

    // pool + head
    k_pool<<<DIV_UP(N, 256), 128, 0, stream>>>(bufB, batch, pooled, counts, N);
    k_mlp<<<G, 64, 0, stream>>>(pooled, counts, Wc1, bc1, Wc2, bc2, out, G);
}

// Round 3
// 628.753 us; speedup vs baseline: 1.4133x; 1.0149x over previous
//
#include <hip/hip_runtime.h>

#define DIV_UP(a,b) (((a)+(b)-1)/(b))

// ---------------- CSR build ----------------

__global__ void k_count(const int* __restrict__ dst, int* __restrict__ deg, int E) {
    int e = blockIdx.x * blockDim.x + threadIdx.x;
    if (e < E) atomicAdd(&deg[dst[e]], 1);
}

__global__ void k_blocksum(const int* __restrict__ deg, int* __restrict__ bsum, int N) {
    __shared__ int s[1024];
    int i = blockIdx.x * 1024 + threadIdx.x;
    s[threadIdx.x] = (i < N) ? deg[i] : 0;
    __syncthreads();
    for (int off = 512; off > 0; off >>= 1) {
        if (threadIdx.x < off) s[threadIdx.x] += s[threadIdx.x + off];
        __syncthreads();
    }
    if (threadIdx.x == 0) bsum[blockIdx.x] = s[0];
}

__global__ void k_scanbsum(const int* __restrict__ bsum, int* __restrict__ boff, int nb) {
    __shared__ int s[1024];
    int v = (threadIdx.x < nb) ? bsum[threadIdx.x] : 0;
    s[threadIdx.x] = v;
    __syncthreads();
    for (int off = 1; off < 1024; off <<= 1) {
        int t = (threadIdx.x >= off) ? s[threadIdx.x - off] : 0;
        __syncthreads();
        s[threadIdx.x] += t;
        __syncthreads();
    }
    if (threadIdx.x < nb) boff[threadIdx.x] = s[threadIdx.x] - v;
}

__global__ void k_scanfinal(const int* __restrict__ deg, const int* __restrict__ boff,
                            int* __restrict__ rowptr, int* __restrict__ cursor,
                            float* __restrict__ inv_sqrt, int N) {
    __shared__ int s[1024];
    int i = blockIdx.x * 1024 + threadIdx.x;
    int v = (i < N) ? deg[i] : 0;
    s[threadIdx.x] = v;
    __syncthreads();
    for (int off = 1; off < 1024; off <<= 1) {
        int t = (threadIdx.x >= off) ? s[threadIdx.x - off] : 0;
        __syncthreads();
        s[threadIdx.x] += t;
        __syncthreads();
    }
    if (i < N) {
        int excl = s[threadIdx.x] - v + boff[blockIdx.x];
        rowptr[i] = excl;
        cursor[i] = excl;
        inv_sqrt[i] = rsqrtf((float)(v + 1));   // +1: self-loop
        if (i == N - 1) rowptr[N] = excl + v;
    }
}

__global__ void k_fill(const int* __restrict__ src, const int* __restrict__ dst,
                       int* __restrict__ cursor, int* __restrict__ col, int E) {
    int e = blockIdx.x * blockDim.x + threadIdx.x;
    if (e < E) {
        int p = atomicAdd(&cursor[dst[e]], 1);
        col[p] = src[e];
    }
}

// ---------------- Register-tiled GEMM ----------------

__global__ __launch_bounds__(256, 3) void k_gemm_rt(const float* __restrict__ in,
                          const float* __restrict__ W,
                          const float* __restrict__ inv_sqrt,
                          float* __restrict__ out, int N) {
    __shared__ float xsT[32][132];
    __shared__ float ws[32][132];

    const int t = threadIdx.x;
    const int row0 = blockIdx.x * 128;
    const int lane = t & 63;
    const int wave = t >> 6;
    const int rg = ((wave >> 1) << 3) + (lane >> 3);  // 0..15 row group
    const int cg = ((wave & 1) << 3) + (lane & 7);    // 0..15 col group

    const float4* in4 = (const float4*)in;
    const float4* W4  = (const float4*)W;

    float4 acc[8][2];
    #pragma unroll
    for (int i = 0; i < 8; i++) {
        acc[i][0] = make_float4(0.f, 0.f, 0.f, 0.f);
        acc[i][1] = make_float4(0.f, 0.f, 0.f, 0.f);
    }

    const bool full = (row0 + 128 <= N);

    for (int kt = 0; kt < 4; kt++) {
        #pragma unroll
        for (int i = 0; i < 4; i++) {
            int idx = t + i * 256;
            int r  = idx >> 3;
            int c4 = idx & 7;
            int row = row0 + r;
            float4 v = make_float4(0.f, 0.f, 0.f, 0.f);
            if (full || row < N) v = in4[(size_t)row * 32 + kt * 8 + c4];
            xsT[c4 * 4 + 0][r] = v.x;
            xsT[c4 * 4 + 1][r] = v.y;
            xsT[c4 * 4 + 2][r] = v.z;
            xsT[c4 * 4 + 3][r] = v.w;
        }
        #pragma unroll
        for (int i = 0; i < 4; i++) {
            int idx = t + i * 256;
            int kk = idx >> 5;
            int c4 = idx & 31;
            *(float4*)&ws[kk][c4 * 4] = W4[(size_t)(kt * 32 + kk) * 32 + c4];
        }
        __syncthreads();

        #pragma unroll 8
        for (int k = 0; k < 32; k++) {
            float4 a0 = *(const float4*)&xsT[k][rg * 8];
            float4 a1 = *(const float4*)&xsT[k][rg * 8 + 4];
            float4 b0 = *(const float4*)&ws[k][cg * 8];
            float4 b1 = *(const float4*)&ws[k][cg * 8 + 4];
            float av[8] = {a0.x, a0.y, a0.z, a0.w, a1.x, a1.y, a1.z, a1.w};
            #pragma unroll
            for (int i = 0; i < 8; i++) {
                acc[i][0].x += av[i] * b0.x;
                acc[i][0].y += av[i] * b0.y;
                acc[i][0].z += av[i] * b0.z;
                acc[i][0].w += av[i] * b0.w;
                acc[i][1].x += av[i] * b1.x;
                acc[i][1].y += av[i] * b1.y;
                acc[i][1].z += av[i] * b1.z;
                acc[i][1].w += av[i] * b1.w;
            }
        }
        __syncthreads();
    }

    #pragma unroll
    for (int i = 0; i < 8; i++) {
        int row = row0 + rg * 8 + i;
        if (full || row < N) {
            float s = inv_sqrt[row];
            float4 o0 = acc[i][0], o1 = acc[i][1];
            o0.x *= s; o0.y *= s; o0.z *= s; o0.w *= s;
            o1.x *= s; o1.y *= s; o1.z *= s; o1.w *= s;
            float4* o = (float4*)(out + (size_t)row * 128);
            o[cg * 2]     = o0;
            o[cg * 2 + 1] = o1;
        }
    }
}

// ---------------- Aggregate ----------------
// h[n] = relu(inv_sqrt[n]*(sum_{e in CSR[n]} g[col[e]] + g[n]) + b)
// one wave per node, float2 per lane. Unrolled x8 with predicated dummy loads
// (dummy -> self row, L1-resident) so each wave keeps 8 gathers in flight.

__global__ __launch_bounds__(256) void k_aggregate(const float* __restrict__ g,
                            const int* __restrict__ rowptr,
                            const int* __restrict__ col, const float* __restrict__ inv_sqrt,
                            const float* __restrict__ bias, float* __restrict__ out, int N) {
    int wid  = (blockIdx.x * blockDim.x + threadIdx.x) >> 6;   // node
    int lane = threadIdx.x & 63;
    if (wid >= N) return;

    int start = rowptr[wid];
    int end   = rowptr[wid + 1];

    const float2* g2 = (const float2*)g;
    float accx = 0.f, accy = 0.f;

    for (int tt = start; tt < end; tt += 8) {
        int idx[8];
        #pragma unroll
        for (int i = 0; i < 8; i++)
            idx[i] = (tt + i < end) ? col[tt + i] : wid;
        float2 v[8];
        #pragma unroll
        for (int i = 0; i < 8; i++)
            v[i] = g2[(size_t)idx[i] * 64 + lane];
        #pragma unroll
        for (int i = 0; i < 8; i++) {
            if (tt + i < end) { accx += v[i].x; accy += v[i].y; }
        }
    }

    float2 sv = g2[(size_t)wid * 64 + lane];
    accx += sv.x;
    accy += sv.y;

    float is = inv_sqrt[wid];
    float2 b = ((const float2*)bias)[lane];
    float ox = fmaxf(is * accx + b.x, 0.f);
    float oy = fmaxf(is * accy + b.y, 0.f);
    ((float2*)(out + (size_t)wid * 128))[lane] = make_float2(ox, oy);
}

// ---------------- Pool ----------------

__global__ void k_pool(const float* __restrict__ h, const int* __restrict__ batch,
                       float* __restrict__ pooled, int* __restrict__ counts, int N) {
    int f = threadIdx.x;            // 0..127
    int start = blockIdx.x * 256;
    int end = start + 256; if (end > N) end = N;
    if (start >= N) return;

    int cur = batch[start];
    float acc = 0.f;
    int cnt = 0;
    for (int r = start; r < end; r++) {
        int gi = batch[r];
        if (gi != cur) {
            atomicAdd(&pooled[(size_t)cur * 128 + f], acc);
            if (f == 0) atomicAdd(&counts[cur], cnt);
            acc = 0.f; cnt = 0; cur = gi;
        }
        acc += h[(size_t)r * 128 + f];
        cnt++;
    }
    atomicAdd(&pooled[(size_t)cur * 128 + f], acc);
    if (f == 0) atomicAdd(&counts[cur], cnt);
}

// ---------------- MLP head ----------------

__global__ void k_mlp(const float* __restrict__ pooled, const int* __restrict__ counts,
                      const float* __restrict__ Wc1, const float* __restrict__ bc1,
                      const float* __restrict__ Wc2, const float* __restrict__ bc2,
                      float* __restrict__ out, int G) {
    int g = blockIdx.x;
    int j = threadIdx.x;    // 0..63
    __shared__ float pm[128];
    __shared__ float z[64];

    float invc = 1.0f / fmaxf((float)counts[g], 1.0f);
    pm[j]      = pooled[(size_t)g * 128 + j] * invc;
    pm[j + 64] = pooled[(size_t)g * 128 + 64 + j] * invc;
    __syncthreads();

    float a = bc1[j];
    #pragma unroll 8
    for (int k = 0; k < 128; k++) a += pm[k] * Wc1[k * 64 + j];
    z[j] = fmaxf(a, 0.f);
    __syncthreads();

    if (j < 8) {
        float o = bc2[j];
        #pragma unroll 8
        for (int k = 0; k < 64; k++) o += z[k] * Wc2[k * 8 + j];
        out[(size_t)g * 8 + j] = o;
    }
}

// ---------------- launch ----------------

extern "C" void kernel_launch(void* const* d_in, const int* in_sizes, int n_in,
                              void* d_out, int out_size, void* d_ws, size_t ws_size,
                              hipStream_t stream) {
    const float* x    = (const float*)d_in[0];
    const int*   ei   = (const int*)d_in[1];
    const int*   batch= (const int*)d_in[2];
    const float* W1   = (const float*)d_in[4];
    const float* b1   = (const float*)d_in[5];
    const float* W2   = (const float*)d_in[6];
    const float* b2   = (const float*)d_in[7];
    const float* Wc1  = (const float*)d_in[8];
    const float* bc1  = (const float*)d_in[9];
    const float* Wc2  = (const float*)d_in[10];
    const float* bc2  = (const float*)d_in[11];
    float* out = (float*)d_out;

    const int N = in_sizes[0] / 128;
    const int E = in_sizes[1] / 2;
    const int G = out_size / 8;

    const int* src = ei;
    const int* dst = ei + E;

    char* p = (char*)d_ws;
    auto alloc = [&](size_t bytes) {
        char* q = p;
        p += (bytes + 255) & ~(size_t)255;
        return q;
    };
    float* bufA     = (float*)alloc((size_t)N * 128 * 4);
    float* bufB     = (float*)alloc((size_t)N * 128 * 4);
    int*   deg      = (int*)  alloc((size_t)N * 4);
    int*   rowptr   = (int*)  alloc(((size_t)N + 1) * 4);
    int*   cursor   = (int*)  alloc((size_t)N * 4);
    int*   colA     = (int*)  alloc((size_t)E * 4);
    float* inv_sqrt = (float*)alloc((size_t)N * 4);
    int*   bsum     = (int*)  alloc(1024 * 4);
    int*   boff     = (int*)  alloc(1024 * 4);
    float* pooled   = (float*)alloc((size_t)G * 128 * 4);
    int*   counts   = (int*)  alloc((size_t)G * 4);

    const int nb = DIV_UP(N, 1024);

    hipMemsetAsync(deg, 0, (size_t)N * 4, stream);
    hipMemsetAsync(pooled, 0, (size_t)G * 128 * 4, stream);
    hipMemsetAsync(counts, 0, (size_t)G * 4, stream);

    // CSR build
    k_count<<<DIV_UP(E, 256), 256, 0, stream>>>(dst, deg, E);
    k_blocksum<<<nb, 1024, 0, stream>>>(deg, bsum, N);
    k_scanbsum<<<1, 1024, 0, stream>>>(bsum, boff, nb);
    k_scanfinal<<<nb, 1024, 0, stream>>>(deg, boff, rowptr, cursor, inv_sqrt, N);
    k_fill<<<DIV_UP(E, 256), 256, 0, stream>>>(src, dst, cursor, colA, E);

    // layer 1
    k_gemm_rt<<<DIV_UP(N, 128), 256, 0, stream>>>(x, W1, inv_sqrt, bufA, N);
    k_aggregate<<<DIV_UP(N, 4), 256, 0, stream>>>(bufA, rowptr, colA, inv_sqrt, b1, bufB, N);

    // layer 2
    k_gemm_rt<<<DIV_UP(N, 128), 256, 0, stream>>>(bufB, W2, inv_sqrt, bufA, N);
    k_aggregate<<<DIV_UP(N, 4), 256, 0, stream>>>(bufA, rowptr, colA, inv_sqrt, b2, bufB, N);

    // pool + head
    k_pool<<<DIV_UP(N, 256), 128, 0, stream>>>(bufB, batch, pooled, counts, N);
    k_mlp<<<G, 64, 0, stream>>>(pooled, counts, Wc1, bc1, Wc2, bc2, out, G);
}

// Round 4
// 580.561 us; speedup vs baseline: 1.5306x; 1.0830x over previous
//
#include <hip/hip_runtime.h>

#define DIV_UP(a,b) (((a)+(b)-1)/(b))

#define CH   9216    // edges per partition block
#define CAP  7424    // max edges per 256-node bucket in sortfill (mean 4096)

// ---------------- CSR build: bucketed counting sort ----------------
// bucket = dst >> 8 (256 nodes per bucket)

__global__ __launch_bounds__(256) void k_hist1(const int* __restrict__ dst, int E,
                                               int NBK, int NB1,
                                               int* __restrict__ blk_hist) {
    __shared__ int hist[512];
    for (int i = threadIdx.x; i < NBK; i += 256) hist[i] = 0;
    __syncthreads();
    int base = blockIdx.x * CH;
    int lim = E - base; if (lim > CH) lim = CH;
    for (int i = threadIdx.x; i < lim; i += 256)
        atomicAdd(&hist[dst[base + i] >> 8], 1);
    __syncthreads();
    for (int b = threadIdx.x; b < NBK; b += 256)
        blk_hist[b * NB1 + blockIdx.x] = hist[b];   // bucket-major
}

__global__ __launch_bounds__(1024) void k_scan1(const int* __restrict__ blk_hist,
                                                int* __restrict__ blk_off,
                                                int* __restrict__ bkt_base,
                                                int NBK, int NB1, int E) {
    __shared__ int part[1024];
    int total = NBK * NB1;
    int chunk = DIV_UP(total, 1024);
    int t = threadIdx.x;
    int lo = t * chunk;
    int hi = lo + chunk; if (hi > total) hi = total;
    int s = 0;
    for (int i = lo; i < hi; i++) s += blk_hist[i];
    part[t] = s;
    __syncthreads();
    for (int o = 1; o < 1024; o <<= 1) {
        int v = (t >= o) ? part[t - o] : 0;
        __syncthreads();
        part[t] += v;
        __syncthreads();
    }
    int run = part[t] - s;   // exclusive prefix of this thread's chunk
    for (int i = lo; i < hi; i++) {
        blk_off[i] = run;
        if (i % NB1 == 0) bkt_base[i / NB1] = run;
        run += blk_hist[i];
    }
    if (t == 0) bkt_base[NBK] = E;
}

__global__ __launch_bounds__(256) void k_scatter1(const int* __restrict__ src,
                                                  const int* __restrict__ dst, int E,
                                                  int NBK, int NB1,
                                                  const int* __restrict__ blk_off,
                                                  unsigned int* __restrict__ part_arr) {
    __shared__ unsigned int   stage[CH];
    __shared__ unsigned short bko[CH];
    __shared__ int hist[512];
    __shared__ int cur[512];
    __shared__ int off[512];

    int t = threadIdx.x;
    hist[t] = 0; hist[t + 256] = 0;
    __syncthreads();

    int base = blockIdx.x * CH;
    int lim = E - base; if (lim > CH) lim = CH;

    for (int i = t; i < lim; i += 256)
        atomicAdd(&hist[dst[base + i] >> 8], 1);
    __syncthreads();

    // inclusive Hillis-Steele over 512 slots (256 threads, 2 slots each)
    int c0 = hist[t], c1 = hist[t + 256];
    for (int o = 1; o < 512; o <<= 1) {
        int v0 = (t >= o) ? hist[t - o] : 0;
        int v1 = hist[t + 256 - o];
        __syncthreads();
        hist[t] += v0;
        hist[t + 256] += v1;
        __syncthreads();
    }
    int e0 = hist[t] - c0;          // exclusive
    int e1 = hist[t + 256] - c1;
    cur[t] = e0; cur[t + 256] = e1;
    if (t < NBK)       off[t]       = blk_off[t * NB1 + blockIdx.x] - e0;
    if (t + 256 < NBK) off[t + 256] = blk_off[(t + 256) * NB1 + blockIdx.x] - e1;
    __syncthreads();

    // group edges by bucket in LDS
    for (int i = t; i < lim; i += 256) {
        int d = dst[base + i];
        int sv = src[base + i];
        int b = d >> 8;
        int slot = atomicAdd(&cur[b], 1);
        stage[slot] = ((unsigned int)sv << 8) | (unsigned int)(d & 255);
        bko[slot] = (unsigned short)b;
    }
    __syncthreads();

    // coalesced run copy-out
    for (int i = t; i < lim; i += 256) {
        int b = bko[i];
        part_arr[off[b] + i] = stage[i];
    }
}

__global__ __launch_bounds__(256) void k_sortfill(const unsigned int* __restrict__ part_arr,
                                                  const int* __restrict__ bkt_base,
                                                  int N, int E,
                                                  int* __restrict__ col,
                                                  int* __restrict__ rowptr,
                                                  float* __restrict__ inv_sqrt) {
    __shared__ unsigned int in_[CAP];
    __shared__ int outS[CAP];
    __shared__ int hist[256];
    __shared__ int scn[256];
    __shared__ int cur[256];

    int b = blockIdx.x;
    int base = bkt_base[b];
    int nb   = bkt_base[b + 1] - base;
    int t = threadIdx.x;

    hist[t] = 0;
    __syncthreads();

    for (int i = t; i < nb; i += 256) {
        unsigned int pk = part_arr[base + i];
        in_[i] = pk;
        atomicAdd(&hist[pk & 255u], 1);
    }
    __syncthreads();

    int cnt = hist[t];
    for (int o = 1; o < 256; o <<= 1) {
        int v = (t >= o) ? hist[t - o] : 0;
        __syncthreads();
        hist[t] += v;
        __syncthreads();
    }
    int excl = hist[t] - cnt;
    scn[t] = excl;
    cur[t] = 0;
    __syncthreads();

    for (int i = t; i < nb; i += 256) {
        unsigned int pk = in_[i];
        int d = (int)(pk & 255u);
        int r = atomicAdd(&cur[d], 1);
        outS[scn[d] + r] = (int)(pk >> 8);
    }
    __syncthreads();

    for (int i = t; i < nb; i += 256) col[base + i] = outS[i];

    int node = b * 256 + t;
    if (node < N) {
        rowptr[node] = base + excl;
        inv_sqrt[node] = rsqrtf((float)(cnt + 1));   // +1: self-loop
    }
    if (b == 0 && t == 0) rowptr[N] = E;
}

// ---------------- Register-tiled GEMM ----------------

__global__ __launch_bounds__(256, 3) void k_gemm_rt(const float* __restrict__ in,
                          const float* __restrict__ W,
                          const float* __restrict__ inv_sqrt,
                          float* __restrict__ out, int N) {
    __shared__ float xsT[32][132];
    __shared__ float ws[32][132];

    const int t = threadIdx.x;
    const int row0 = blockIdx.x * 128;
    const int lane = t & 63;
    const int wave = t >> 6;
    const int rg = ((wave >> 1) << 3) + (lane >> 3);  // 0..15 row group
    const int cg = ((wave & 1) << 3) + (lane & 7);    // 0..15 col group

    const float4* in4 = (const float4*)in;
    const float4* W4  = (const float4*)W;

    float4 acc[8][2];
    #pragma unroll
    for (int i = 0; i < 8; i++) {
        acc[i][0] = make_float4(0.f, 0.f, 0.f, 0.f);
        acc[i][1] = make_float4(0.f, 0.f, 0.f, 0.f);
    }

    const bool full = (row0 + 128 <= N);

    for (int kt = 0; kt < 4; kt++) {
        #pragma unroll
        for (int i = 0; i < 4; i++) {
            int idx = t + i * 256;
            int r  = idx >> 3;
            int c4 = idx & 7;
            int row = row0 + r;
            float4 v = make_float4(0.f, 0.f, 0.f, 0.f);
            if (full || row < N) v = in4[(size_t)row * 32 + kt * 8 + c4];
            xsT[c4 * 4 + 0][r] = v.x;
            xsT[c4 * 4 + 1][r] = v.y;
            xsT[c4 * 4 + 2][r] = v.z;
            xsT[c4 * 4 + 3][r] = v.w;
        }
        #pragma unroll
        for (int i = 0; i < 4; i++) {
            int idx = t + i * 256;
            int kk = idx >> 5;
            int c4 = idx & 31;
            *(float4*)&ws[kk][c4 * 4] = W4[(size_t)(kt * 32 + kk) * 32 + c4];
        }
        __syncthreads();

        #pragma unroll 8
        for (int k = 0; k < 32; k++) {
            float4 a0 = *(const float4*)&xsT[k][rg * 8];
            float4 a1 = *(const float4*)&xsT[k][rg * 8 + 4];
            float4 b0 = *(const float4*)&ws[k][cg * 8];
            float4 b1 = *(const float4*)&ws[k][cg * 8 + 4];
            float av[8] = {a0.x, a0.y, a0.z, a0.w, a1.x, a1.y, a1.z, a1.w};
            #pragma unroll
            for (int i = 0; i < 8; i++) {
                acc[i][0].x += av[i] * b0.x;
                acc[i][0].y += av[i] * b0.y;
                acc[i][0].z += av[i] * b0.z;
                acc[i][0].w += av[i] * b0.w;
                acc[i][1].x += av[i] * b1.x;
                acc[i][1].y += av[i] * b1.y;
                acc[i][1].z += av[i] * b1.z;
                acc[i][1].w += av[i] * b1.w;
            }
        }
        __syncthreads();
    }

    #pragma unroll
    for (int i = 0; i < 8; i++) {
        int row = row0 + rg * 8 + i;
        if (full || row < N) {
            float s = inv_sqrt[row];
            float4 o0 = acc[i][0], o1 = acc[i][1];
            o0.x *= s; o0.y *= s; o0.z *= s; o0.w *= s;
            o1.x *= s; o1.y *= s; o1.z *= s; o1.w *= s;
            float4* o = (float4*)(out + (size_t)row * 128);
            o[cg * 2]     = o0;
            o[cg * 2 + 1] = o1;
        }
    }
}

// ---------------- Aggregate ----------------

__global__ __launch_bounds__(256) void k_aggregate(const float* __restrict__ g,
                            const int* __restrict__ rowptr,
                            const int* __restrict__ col, const float* __restrict__ inv_sqrt,
                            const float* __restrict__ bias, float* __restrict__ out, int N) {
    int wid  = (blockIdx.x * blockDim.x + threadIdx.x) >> 6;   // node
    int lane = threadIdx.x & 63;
    if (wid >= N) return;

    int start = rowptr[wid];
    int end   = rowptr[wid + 1];

    const float2* g2 = (const float2*)g;
    float accx = 0.f, accy = 0.f;

    for (int tt = start; tt < end; tt += 8) {
        int idx[8];
        #pragma unroll
        for (int i = 0; i < 8; i++)
            idx[i] = (tt + i < end) ? col[tt + i] : wid;
        float2 v[8];
        #pragma unroll
        for (int i = 0; i < 8; i++)
            v[i] = g2[(size_t)idx[i] * 64 + lane];
        #pragma unroll
        for (int i = 0; i < 8; i++) {
            if (tt + i < end) { accx += v[i].x; accy += v[i].y; }
        }
    }

    float2 sv = g2[(size_t)wid * 64 + lane];
    accx += sv.x;
    accy += sv.y;

    float is = inv_sqrt[wid];
    float2 b = ((const float2*)bias)[lane];
    float ox = fmaxf(is * accx + b.x, 0.f);
    float oy = fmaxf(is * accy + b.y, 0.f);
    ((float2*)(out + (size_t)wid * 128))[lane] = make_float2(ox, oy);
}

// ---------------- Pool ----------------

__global__ void k_pool(const float* __restrict__ h, const int* __restrict__ batch,
                       float* __restrict__ pooled, int* __restrict__ counts, int N) {
    int f = threadIdx.x;            // 0..127
    int start = blockIdx.x * 256;
    int end = start + 256; if (end > N) end = N;
    if (start >= N) return;

    int cur = batch[start];
    float acc = 0.f;
    int cnt = 0;
    for (int r = start; r < end; r++) {
        int gi = batch[r];
        if (gi != cur) {
            atomicAdd(&pooled[(size_t)cur * 128 + f], acc);
            if (f == 0) atomicAdd(&counts[cur], cnt);
            acc = 0.f; cnt = 0; cur = gi;
        }
        acc += h[(size_t)r * 128 + f];
        cnt++;
    }
    atomicAdd(&pooled[(size_t)cur * 128 + f], acc);
    if (f == 0) atomicAdd(&counts[cur], cnt);
}

// ---------------- MLP head ----------------

__global__ void k_mlp(const float* __restrict__ pooled, const int* __restrict__ counts,
                      const float* __restrict__ Wc1, const float* __restrict__ bc1,
                      const float* __restrict__ Wc2, const float* __restrict__ bc2,
                      float* __restrict__ out, int G) {
    int g = blockIdx.x;
    int j = threadIdx.x;    // 0..63
    __shared__ float pm[128];
    __shared__ float z[64];

    float invc = 1.0f / fmaxf((float)counts[g], 1.0f);
    pm[j]      = pooled[(size_t)g * 128 + j] * invc;
    pm[j + 64] = pooled[(size_t)g * 128 + 64 + j] * invc;
    __syncthreads();

    float a = bc1[j];
    #pragma unroll 8
    for (int k = 0; k < 128; k++) a += pm[k] * Wc1[k * 64 + j];
    z[j] = fmaxf(a, 0.f);
    __syncthreads();

    if (j < 8) {
        float o = bc2[j];
        #pragma unroll 8
        for (int k = 0; k < 64; k++) o += z[k] * Wc2[k * 8 + j];
        out[(size_t)g * 8 + j] = o;
    }
}

// ---------------- launch ----------------

extern "C" void kernel_launch(void* const* d_in, const int* in_sizes, int n_in,
                              void* d_out, int out_size, void* d_ws, size_t ws_size,
                              hipStream_t stream) {
    const float* x    = (const float*)d_in[0];
    const int*   ei   = (const int*)d_in[1];
    const int*   batch= (const int*)d_in[2];
    const float* W1   = (const float*)d_in[4];
    const float* b1   = (const float*)d_in[5];
    const float* W2   = (const float*)d_in[6];
    const float* b2   = (const float*)d_in[7];
    const float* Wc1  = (const float*)d_in[8];
    const float* bc1  = (const float*)d_in[9];
    const float* Wc2  = (const float*)d_in[10];
    const float* bc2  = (const float*)d_in[11];
    float* out = (float*)d_out;

    const int N = in_sizes[0] / 128;
    const int E = in_sizes[1] / 2;
    const int G = out_size / 8;

    const int* src = ei;
    const int* dst = ei + E;

    const int NBK = DIV_UP(N, 256);     // buckets of 256 nodes
    const int NB1 = DIV_UP(E, CH);      // partition blocks

    char* p = (char*)d_ws;
    auto alloc = [&](size_t bytes) {
        char* q = p;
        p += (bytes + 255) & ~(size_t)255;
        return q;
    };
    float* bufA     = (float*)alloc((size_t)N * 128 * 4);
    float* bufB     = (float*)alloc((size_t)N * 128 * 4);
    int*   rowptr   = (int*)  alloc(((size_t)N + 1) * 4);
    int*   colA     = (int*)  alloc((size_t)E * 4);
    float* inv_sqrt = (float*)alloc((size_t)N * 4);
    int*   blk_hist = (int*)  alloc((size_t)NBK * NB1 * 4);
    int*   blk_off  = (int*)  alloc((size_t)NBK * NB1 * 4);
    int*   bkt_base = (int*)  alloc(((size_t)NBK + 1) * 4);
    float* pooled   = (float*)alloc((size_t)G * 128 * 4);
    int*   counts   = (int*)  alloc((size_t)G * 4);

    // part_arr aliases bufA: consumed by k_sortfill before the first GEMM writes bufA
    unsigned int* part_arr = (unsigned int*)bufA;

    hipMemsetAsync(pooled, 0, (size_t)G * 128 * 4, stream);
    hipMemsetAsync(counts, 0, (size_t)G * 4, stream);

    // CSR build (bucketed counting sort)
    k_hist1<<<NB1, 256, 0, stream>>>(dst, E, NBK, NB1, blk_hist);
    k_scan1<<<1, 1024, 0, stream>>>(blk_hist, blk_off, bkt_base, NBK, NB1, E);
    k_scatter1<<<NB1, 256, 0, stream>>>(src, dst, E, NBK, NB1, blk_off, part_arr);
    k_sortfill<<<NBK, 256, 0, stream>>>(part_arr, bkt_base, N, E, colA, rowptr, inv_sqrt);

    // layer 1
    k_gemm_rt<<<DIV_UP(N, 128), 256, 0, stream>>>(x, W1, inv_sqrt, bufA, N);
    k_aggregate<<<DIV_UP(N, 4), 256, 0, stream>>>(bufA, rowptr, colA, inv_sqrt, b1, bufB, N);

    // layer 2
    k_gemm_rt<<<DIV_UP(N, 128), 256, 0, stream>>>(bufB, W2, inv_sqrt, bufA, N);
    k_aggregate<<<DIV_UP(N, 4), 256, 0, stream>>>(bufA, rowptr, colA, inv_sqrt, b2, bufB, N);

    // pool + head
    k_pool<<<DIV_UP(N, 256), 128, 0, stream>>>(bufB, batch, pooled, counts, N);
    k_mlp<<<G, 64, 0, stream>>>(pooled, counts, Wc1, bc1, Wc2, bc2, out, G);
}